// Round 2
// baseline (1520.101 us; speedup 1.0000x reference)
//
#include <hip/hip_runtime.h>
#include <hip/hip_bf16.h>
#include <math.h>

#define NN 8192
#define NE 262144
#define EA (NE + NN)          // edges + self loops
#define SLOPE 0.2f
#define TH2 0.25f             // THRESH^2 : dist<0.5  <=>  d2<0.25

__device__ __forceinline__ float lrelu(float x) { return x > 0.f ? x : SLOPE * x; }

__device__ __forceinline__ float sel8(const float* v, int i) {
  float r = v[0];
#pragma unroll
  for (int q = 1; q < 8; ++q) r = (i == q) ? v[q] : r;
  return r;
}

// ---------------- K1: h = x@W1 (4 nodes/block, W1 value reused x4), a_s/a_d ----------------
__global__ void k_gemm1(const float* __restrict__ x, const float* __restrict__ W1,
                        const float* __restrict__ as1, const float* __restrict__ ad1,
                        float* __restrict__ h, float* __restrict__ a_s,
                        float* __restrict__ a_d) {
  const int nb = blockIdx.x << 2;
  const int t = threadIdx.x;
  __shared__ float xs[4][128];
  if (t < 128) ((float4*)xs)[t] = ((const float4*)(x + (size_t)nb * 128))[t];
  __syncthreads();
  float ac[4] = {0.f, 0.f, 0.f, 0.f};
  const float* wp = W1 + t;            // W1 [128][256]
#pragma unroll 4
  for (int k = 0; k < 128; ++k) {
    float w = wp[(size_t)k << 8];
    ac[0] = fmaf(xs[0][k], w, ac[0]);
    ac[1] = fmaf(xs[1][k], w, ac[1]);
    ac[2] = fmaf(xs[2][k], w, ac[2]);
    ac[3] = fmaf(xs[3][k], w, ac[3]);
  }
  const float as1t = as1[t], ad1t = ad1[t];
#pragma unroll
  for (int i = 0; i < 4; ++i) {
    h[((size_t)(nb + i) << 8) + t] = ac[i];
    float av = ac[i] * as1t;
    float dv = ac[i] * ad1t;
#pragma unroll
    for (int m = 32; m >= 1; m >>= 1) {
      av += __shfl_xor(av, m, 64);
      dv += __shfl_xor(dv, m, 64);
    }
    if ((t & 63) == 0) {
      a_s[((nb + i) << 2) + (t >> 6)] = av;
      a_d[((nb + i) << 2) + (t >> 6)] = dv;
    }
  }
}

// ---------------- CSR build ----------------
__global__ void k_init(int* __restrict__ cnt) {
  int i = blockIdx.x * 256 + threadIdx.x;
  if (i < NN) cnt[i] = 1;               // self loop pre-counted
}
__global__ void k_hist(const int* __restrict__ ei, int* __restrict__ cnt) {
  int e = blockIdx.x * 256 + threadIdx.x;
  if (e < NE) atomicAdd(&cnt[ei[NE + e]], 1);
}
__global__ void k_scan(const int* __restrict__ cnt, int* __restrict__ start,
                       int* __restrict__ cursor) {
  __shared__ int s[1024];
  const int t = threadIdx.x;
  const int base = t << 3;
  int c[8];
  int run = 0;
#pragma unroll
  for (int i = 0; i < 8; ++i) { c[i] = cnt[base + i]; run += c[i]; }
  s[t] = run;
  __syncthreads();
  const int total = run;
  for (int off = 1; off < 1024; off <<= 1) {
    int v = (t >= off) ? s[t - off] : 0;
    __syncthreads();
    s[t] += v;
    __syncthreads();
  }
  int o = s[t] - total;                 // exclusive prefix
#pragma unroll
  for (int i = 0; i < 8; ++i) {
    start[base + i] = o;
    cursor[base + i] = o;
    o += c[i];
  }
}
__global__ void k_scatter(const int* __restrict__ ei, int* __restrict__ cursor,
                          int* __restrict__ eidx) {
  int e = blockIdx.x * 256 + threadIdx.x;
  if (e >= EA) return;
  int src, dst;
  if (e < NE) { src = ei[e]; dst = ei[NE + e]; } else { src = dst = e - NE; }
  int slot = atomicAdd(&cursor[dst], 1);
  eidx[slot] = src;
}

// ---------------- K_node: fused segment max + softmax + aggregate + post ----------------
// one block (256 threads) per dst node; thread t owns channel t; no f32 atomics.
__global__ void k_node(const int* __restrict__ start, const int* __restrict__ cnt,
                       const int* __restrict__ eidx, const float* __restrict__ a_s,
                       const float* __restrict__ a_d, const float* __restrict__ h,
                       const float* __restrict__ b1, const float* __restrict__ W2,
                       const float* __restrict__ as2, const float* __restrict__ ad2,
                       float* __restrict__ f, float* __restrict__ sq,
                       float* __restrict__ h2, float* __restrict__ s2,
                       float* __restrict__ t2) {
  const int n = blockIdx.x, t = threadIdx.x;
  __shared__ float red[16];             // [wave][head]
  __shared__ float hl[256];
  __shared__ float r2[4];
  __shared__ float h2l[16];
  const int st = start[n];
  const int deg = cnt[n];
  const float4 ad4 = *(const float4*)(a_d + ((size_t)n << 2));
  // pass1: per-head max over incoming edges
  float pm0 = -INFINITY, pm1 = -INFINITY, pm2 = -INFINITY, pm3 = -INFINITY;
  for (int e = t; e < deg; e += 256) {
    int src = eidx[st + e];
    float4 s4 = *(const float4*)(a_s + ((size_t)src << 2));
    pm0 = fmaxf(pm0, lrelu(s4.x + ad4.x));
    pm1 = fmaxf(pm1, lrelu(s4.y + ad4.y));
    pm2 = fmaxf(pm2, lrelu(s4.z + ad4.z));
    pm3 = fmaxf(pm3, lrelu(s4.w + ad4.w));
  }
#pragma unroll
  for (int m = 32; m >= 1; m >>= 1) {
    pm0 = fmaxf(pm0, __shfl_xor(pm0, m, 64));
    pm1 = fmaxf(pm1, __shfl_xor(pm1, m, 64));
    pm2 = fmaxf(pm2, __shfl_xor(pm2, m, 64));
    pm3 = fmaxf(pm3, __shfl_xor(pm3, m, 64));
  }
  if ((t & 63) == 0) {
    const int w = t >> 6;
    red[(w << 2) + 0] = pm0;
    red[(w << 2) + 1] = pm1;
    red[(w << 2) + 2] = pm2;
    red[(w << 2) + 3] = pm3;
  }
  __syncthreads();
  const int hd = t >> 6;                // head of this channel
  const float mhead = fmaxf(fmaxf(red[0 + hd], red[4 + hd]),
                            fmaxf(red[8 + hd], red[12 + hd]));
  const float adh = (hd == 0) ? ad4.x : (hd == 1) ? ad4.y : (hd == 2) ? ad4.z : ad4.w;
  // pass2: den and unnormalized aggregate (den identical across wave lanes)
  float den = 0.f, acc = 0.f;
  for (int e = 0; e < deg; ++e) {
    int src = eidx[st + e];                          // uniform
    float av = a_s[((size_t)src << 2) + hd];         // broadcast within wave
    float ez = __expf(lrelu(av + adh) - mhead);
    den += ez;
    acc = fmaf(ez, h[((size_t)src << 8) + t], acc);  // coalesced row read
  }
  float v = acc / den + b1[t];
  float h1 = v > 0.f ? v : (__expf(v) - 1.f);        // elu
  f[((size_t)n << 8) + t] = h1;
  hl[t] = h1;
  float s = h1 * h1;
#pragma unroll
  for (int m = 32; m >= 1; m >>= 1) s += __shfl_xor(s, m, 64);
  if ((t & 63) == 0) r2[t >> 6] = s;
  __syncthreads();
  if (t < 16) {
    float a = 0.f;
#pragma unroll 8
    for (int c = 0; c < 256; ++c) a = fmaf(hl[c], W2[(c << 4) + t], a);
    h2[((size_t)n << 4) + t] = a;
    h2l[t] = a;
  }
  if (t == 0) sq[n] = r2[0] + r2[1] + r2[2] + r2[3];
  __syncthreads();
  if (t == 0) {
    float ss = 0.f;
#pragma unroll
    for (int o = 0; o < 16; ++o) ss += h2l[o] * as2[o];
    s2[n] = ss;
  } else if (t == 1) {
    float tt = 0.f;
#pragma unroll
    for (int o = 0; o < 16; ++o) tt += h2l[o] * ad2[o];
    t2[n] = tt;
  }
}

// ---------------- K_conv2: fused dist-mask + dense GAT softmax + PV + log_softmax ----------
// grid 256 x 256 threads. BI=32 rows/block (8 rows/wave, broadcast A), BJ=128 (2 cols/lane),
// K=256 in 2 chunks of 128. All softmax state register-replicated per wave.
__launch_bounds__(256, 1)
__global__ void k_conv2(const float* __restrict__ f, const float* __restrict__ sq,
                        const float* __restrict__ h2, const float* __restrict__ s2,
                        const float* __restrict__ t2, const float* __restrict__ b2,
                        float* __restrict__ out) {
  __shared__ float4 fi[32 * 65];        // [32 rows][64 f4 + 1 pad]  (full K)
  __shared__ float4 fjc[128 * 33];      // [128 cols][32 f4 + 1 pad] (K chunk of 128)
  __shared__ __align__(16) float Pt[32 * 132];
  __shared__ __align__(16) float h2t[16 * 132];

  const int t = threadIdx.x;
  const int lane = t & 63;
  const int w = t >> 6;                 // wave id 0..3
  const int wrow8 = w << 3;             // first block-row of this wave
  const int i0 = blockIdx.x << 5;

  // stage fi (32 rows x 1KB), coalesced
  {
    const int k4 = t & 63;
    const int r0 = (t >> 6) << 3;
#pragma unroll
    for (int p = 0; p < 8; ++p) {
      int r = r0 + p;
      fi[r * 65 + k4] = *(const float4*)(f + ((size_t)(i0 + r) << 8) + (k4 << 2));
    }
  }

  float t2i[8], sqi[8], mrow[8], lrow[8];
#pragma unroll
  for (int r = 0; r < 8; ++r) {
    t2i[r] = t2[i0 + wrow8 + r];
    sqi[r] = sq[i0 + wrow8 + r];
    mrow[r] = -INFINITY;
    lrow[r] = 0.f;
  }
  float acc0 = 0.f, acc1 = 0.f;         // PV accumulators (row = lane>>3, ch pair)
  const int pvr = lane >> 3;
  const int pvc = (lane & 7) << 1;

  for (int jt = 0; jt < 64; ++jt) {
    const int j0 = jt << 7;
    float g0[8], g1[8];
#pragma unroll
    for (int r = 0; r < 8; ++r) { g0[r] = 0.f; g1[r] = 0.f; }

#pragma unroll
    for (int kk = 0; kk < 2; ++kk) {
      __syncthreads();                  // prev readers of fjc / Pt / h2t done
      // stage fjc: 128 cols x 512B chunk
      {
        const int k4c = t & 31;
        const int r0c = t >> 5;
#pragma unroll
        for (int p = 0; p < 16; ++p) {
          int r = r0c + (p << 3);
          fjc[r * 33 + k4c] =
              *(const float4*)(f + ((size_t)(j0 + r) << 8) + (kk << 7) + (k4c << 2));
        }
      }
      if (kk == 0) {                    // stage h2t transposed once per j-tile
        const int j = t & 127;
        const int g = t >> 7;
#pragma unroll
        for (int u = 0; u < 2; ++u) {
          int c4 = (g << 1) + u;
          float4 hv = *(const float4*)(h2 + ((size_t)(j0 + j) << 4) + (c4 << 2));
          h2t[((c4 << 2) + 0) * 132 + j] = hv.x;
          h2t[((c4 << 2) + 1) * 132 + j] = hv.y;
          h2t[((c4 << 2) + 2) * 132 + j] = hv.z;
          h2t[((c4 << 2) + 3) * 132 + j] = hv.w;
        }
      }
      __syncthreads();
      // gram: A broadcast (8 rows), B per-lane (2 cols)
      const int kko = kk << 5;          // f4 offset into fi row
      const float4* bp0 = fjc + lane * 33;
      const float4* bp1 = fjc + (lane + 64) * 33;
      const float4* ap = fi + (wrow8)*65 + kko;
#pragma unroll 4
      for (int kq = 0; kq < 32; ++kq) {
        float4 b0 = bp0[kq];
        float4 b1 = bp1[kq];
#pragma unroll
        for (int r = 0; r < 8; ++r) {
          float4 a = ap[r * 65 + kq];
          g0[r] = fmaf(a.x, b0.x, fmaf(a.y, b0.y, fmaf(a.z, b0.z, fmaf(a.w, b0.w, g0[r]))));
          g1[r] = fmaf(a.x, b1.x, fmaf(a.y, b1.y, fmaf(a.z, b1.z, fmaf(a.w, b1.w, g1[r]))));
        }
      }
    }
    // ---- mask + online softmax (per wave; all lanes hold identical m/l per row) ----
    const float sq0 = sq[j0 + lane];
    const float sq1 = sq[j0 + 64 + lane];
    const float sv0 = s2[j0 + lane];
    const float sv1 = s2[j0 + 64 + lane];
    float scale[8];
#pragma unroll
    for (int r = 0; r < 8; ++r) {
      float d20 = sqi[r] + sq0 - 2.f * g0[r];
      float d21 = sqi[r] + sq1 - 2.f * g1[r];
      float e0 = lrelu(sv0 + t2i[r]);
      float e1 = lrelu(sv1 + t2i[r]);
      float s0 = (d20 < TH2) ? e0 : -INFINITY;
      float s1 = (d21 < TH2) ? e1 : -INFINITY;
      float tm = fmaxf(s0, s1);
#pragma unroll
      for (int m = 32; m >= 1; m >>= 1) tm = fmaxf(tm, __shfl_xor(tm, m, 64));
      float mn = fmaxf(mrow[r], tm);
      float mg = (mn == -INFINITY) ? 0.f : mn;
      float sc = (mrow[r] == -INFINITY) ? ((mn == -INFINITY) ? 1.f : 0.f)
                                        : __expf(mrow[r] - mn);
      float p0 = (s0 == -INFINITY) ? 0.f : __expf(s0 - mg);
      float p1 = (s1 == -INFINITY) ? 0.f : __expf(s1 - mg);
      Pt[(wrow8 + r) * 132 + lane] = p0;
      Pt[(wrow8 + r) * 132 + 64 + lane] = p1;
      float ps = p0 + p1;
#pragma unroll
      for (int m = 32; m >= 1; m >>= 1) ps += __shfl_xor(ps, m, 64);
      lrow[r] = lrow[r] * sc + ps;
      mrow[r] = mn;
      scale[r] = sc;
    }
    // ---- PV: wave-local rows; acc = acc*scale + P @ h2t ----
    {
      float sc = sel8(scale, pvr);
      float a0 = acc0 * sc, a1 = acc1 * sc;
      const float* pr = Pt + (size_t)(wrow8 + pvr) * 132;
      const float* ha = h2t + (size_t)pvc * 132;
      const float* hb = ha + 132;
#pragma unroll 8
      for (int j4 = 0; j4 < 32; ++j4) {
        float4 p4 = *(const float4*)(pr + (j4 << 2));
        float4 va = *(const float4*)(ha + (j4 << 2));
        float4 vb = *(const float4*)(hb + (j4 << 2));
        a0 = fmaf(p4.x, va.x, a0); a1 = fmaf(p4.x, vb.x, a1);
        a0 = fmaf(p4.y, va.y, a0); a1 = fmaf(p4.y, vb.y, a1);
        a0 = fmaf(p4.z, va.z, a0); a1 = fmaf(p4.z, vb.z, a1);
        a0 = fmaf(p4.w, va.w, a0); a1 = fmaf(p4.w, vb.w, a1);
      }
      acc0 = a0; acc1 = a1;
    }
  }
  // ---- epilogue: normalize, +b2, log_softmax over 16 ch (8 lanes x 2 ch) ----
  {
    float linv = 1.f / sel8(lrow, pvr);
    float v0 = acc0 * linv + b2[pvc];
    float v1 = acc1 * linv + b2[pvc + 1];
    float mx = fmaxf(v0, v1);
#pragma unroll
    for (int m = 1; m <= 4; m <<= 1) mx = fmaxf(mx, __shfl_xor(mx, m, 8));
    float se = __expf(v0 - mx) + __expf(v1 - mx);
#pragma unroll
    for (int m = 1; m <= 4; m <<= 1) se += __shfl_xor(se, m, 8);
    float lse = mx + logf(se);
    float2 o;
    o.x = v0 - lse;
    o.y = v1 - lse;
    *(float2*)(out + ((size_t)(i0 + wrow8 + pvr) << 4) + pvc) = o;
  }
}

extern "C" void kernel_launch(void* const* d_in, const int* in_sizes, int n_in,
                              void* d_out, int out_size, void* d_ws, size_t ws_size,
                              hipStream_t stream) {
  const float* x   = (const float*)d_in[0];
  const int*   ei  = (const int*)d_in[1];
  const float* W1  = (const float*)d_in[2];
  const float* as1 = (const float*)d_in[3];
  const float* ad1 = (const float*)d_in[4];
  const float* b1  = (const float*)d_in[5];
  const float* W2  = (const float*)d_in[6];
  const float* as2 = (const float*)d_in[7];
  const float* ad2 = (const float*)d_in[8];
  const float* b2  = (const float*)d_in[9];
  float* out = (float*)d_out;

  float* ws = (float*)d_ws;
  float* h      = ws;                         // NN*256
  float* fbuf   = h + (size_t)NN * 256;       // NN*256  (h1; must NOT alias h)
  float* a_s    = fbuf + (size_t)NN * 256;    // NN*4
  float* a_d    = a_s + (size_t)NN * 4;       // NN*4
  float* sq     = a_d + (size_t)NN * 4;       // NN
  float* h2     = sq + NN;                    // NN*16
  float* s2     = h2 + (size_t)NN * 16;       // NN
  float* t2     = s2 + NN;                    // NN
  int* cnt      = (int*)(t2 + NN);            // NN
  int* startp   = cnt + NN;                   // NN
  int* cursor   = startp + NN;                // NN
  int* eidx     = cursor + NN;                // EA

  k_init<<<NN / 256, 256, 0, stream>>>(cnt);
  k_hist<<<NE / 256, 256, 0, stream>>>(ei, cnt);
  k_gemm1<<<NN / 4, 256, 0, stream>>>(x, W1, as1, ad1, h, a_s, a_d);
  k_scan<<<1, 1024, 0, stream>>>(cnt, startp, cursor);
  k_scatter<<<(EA + 255) / 256, 256, 0, stream>>>(ei, cursor, eidx);
  k_node<<<NN, 256, 0, stream>>>(startp, cnt, eidx, a_s, a_d, h, b1, W2, as2, ad2,
                                 fbuf, sq, h2, s2, t2);
  k_conv2<<<NN / 32, 256, 0, stream>>>(fbuf, sq, h2, s2, t2, b2, out);
}

// Round 3
// 311.406 us; speedup vs baseline: 4.8814x; 4.8814x over previous
//
#include <hip/hip_runtime.h>
#include <hip/hip_bf16.h>
#include <math.h>

#define NN 8192
#define NE 262144
#define EA (NE + NN)          // edges + self loops
#define SLOPE 0.2f
#define TH2 0.25f             // THRESH^2 : dist<0.5  <=>  d2<0.25

typedef __bf16 bf16x8 __attribute__((ext_vector_type(8)));
typedef float f32x16 __attribute__((ext_vector_type(16)));

__device__ __forceinline__ float lrelu(float x) { return x > 0.f ? x : SLOPE * x; }

__device__ __forceinline__ void gl_lds16(const void* g, void* l) {
  __builtin_amdgcn_global_load_lds((const __attribute__((address_space(1))) void*)g,
                                   (__attribute__((address_space(3))) void*)l, 16, 0, 0);
}

// ---------------- K1: h = x@W1 (4 nodes/block), a_s/a_d head sums ----------------
__global__ void k_gemm1(const float* __restrict__ x, const float* __restrict__ W1,
                        const float* __restrict__ as1, const float* __restrict__ ad1,
                        float* __restrict__ h, float* __restrict__ a_s,
                        float* __restrict__ a_d) {
  const int nb = blockIdx.x << 2;
  const int t = threadIdx.x;
  __shared__ float xs[4][128];
  if (t < 128) ((float4*)xs)[t] = ((const float4*)(x + (size_t)nb * 128))[t];
  __syncthreads();
  float ac[4] = {0.f, 0.f, 0.f, 0.f};
  const float* wp = W1 + t;            // W1 [128][256]
#pragma unroll 4
  for (int k = 0; k < 128; ++k) {
    float wv = wp[(size_t)k << 8];
    ac[0] = fmaf(xs[0][k], wv, ac[0]);
    ac[1] = fmaf(xs[1][k], wv, ac[1]);
    ac[2] = fmaf(xs[2][k], wv, ac[2]);
    ac[3] = fmaf(xs[3][k], wv, ac[3]);
  }
  const float as1t = as1[t], ad1t = ad1[t];
#pragma unroll
  for (int i = 0; i < 4; ++i) {
    h[((size_t)(nb + i) << 8) + t] = ac[i];
    float av = ac[i] * as1t;
    float dv = ac[i] * ad1t;
#pragma unroll
    for (int m = 32; m >= 1; m >>= 1) {
      av += __shfl_xor(av, m, 64);
      dv += __shfl_xor(dv, m, 64);
    }
    if ((t & 63) == 0) {
      a_s[((nb + i) << 2) + (t >> 6)] = av;
      a_d[((nb + i) << 2) + (t >> 6)] = dv;
    }
  }
}

// ---------------- CSR build ----------------
__global__ void k_init(int* __restrict__ cnt) {
  int i = blockIdx.x * 256 + threadIdx.x;
  if (i < NN) cnt[i] = 1;               // self loop pre-counted
}
__global__ void k_hist(const int* __restrict__ ei, int* __restrict__ cnt) {
  int e = blockIdx.x * 256 + threadIdx.x;
  if (e < NE) atomicAdd(&cnt[ei[NE + e]], 1);
}
__global__ void k_scan(const int* __restrict__ cnt, int* __restrict__ start,
                       int* __restrict__ cursor) {
  __shared__ int s[1024];
  const int t = threadIdx.x;
  const int base = t << 3;
  int c[8];
  int run = 0;
#pragma unroll
  for (int i = 0; i < 8; ++i) { c[i] = cnt[base + i]; run += c[i]; }
  s[t] = run;
  __syncthreads();
  const int total = run;
  for (int off = 1; off < 1024; off <<= 1) {
    int v = (t >= off) ? s[t - off] : 0;
    __syncthreads();
    s[t] += v;
    __syncthreads();
  }
  int o = s[t] - total;                 // exclusive prefix
#pragma unroll
  for (int i = 0; i < 8; ++i) {
    start[base + i] = o;
    cursor[base + i] = o;
    o += c[i];
  }
}
__global__ void k_scatter(const int* __restrict__ ei, int* __restrict__ cursor,
                          int* __restrict__ eidx) {
  int e = blockIdx.x * 256 + threadIdx.x;
  if (e >= EA) return;
  int src, dst;
  if (e < NE) { src = ei[e]; dst = ei[NE + e]; } else { src = dst = e - NE; }
  int slot = atomicAdd(&cursor[dst], 1);
  eidx[slot] = src;
}

// ---------------- K_node: fused segment max + softmax + aggregate + post ----------------
// one block (256 threads) per dst node; thread t owns channel t; no f32 atomics.
// outputs: fbf (bf16 h1), sq (f32), jsg = {(sq-TH2)/2, s2}, t2g, h2g (f32)
__global__ void k_node(const int* __restrict__ start, const int* __restrict__ cnt,
                       const int* __restrict__ eidx, const float* __restrict__ a_s,
                       const float* __restrict__ a_d, const float* __restrict__ h,
                       const float* __restrict__ b1, const float* __restrict__ W2,
                       const float* __restrict__ as2, const float* __restrict__ ad2,
                       __bf16* __restrict__ fbf, float* __restrict__ sq,
                       float2* __restrict__ jsg, float* __restrict__ t2g,
                       float* __restrict__ h2g) {
  const int n = blockIdx.x, t = threadIdx.x;
  __shared__ float red[16];             // [wave][head]
  __shared__ float hl[256];
  __shared__ float r2[4];
  __shared__ float h2l[16];
  const int st = start[n];
  const int deg = cnt[n];
  const float4 ad4 = *(const float4*)(a_d + ((size_t)n << 2));
  // pass1: per-head max over incoming edges
  float pm0 = -INFINITY, pm1 = -INFINITY, pm2 = -INFINITY, pm3 = -INFINITY;
  for (int e = t; e < deg; e += 256) {
    int src = eidx[st + e];
    float4 s4 = *(const float4*)(a_s + ((size_t)src << 2));
    pm0 = fmaxf(pm0, lrelu(s4.x + ad4.x));
    pm1 = fmaxf(pm1, lrelu(s4.y + ad4.y));
    pm2 = fmaxf(pm2, lrelu(s4.z + ad4.z));
    pm3 = fmaxf(pm3, lrelu(s4.w + ad4.w));
  }
#pragma unroll
  for (int m = 32; m >= 1; m >>= 1) {
    pm0 = fmaxf(pm0, __shfl_xor(pm0, m, 64));
    pm1 = fmaxf(pm1, __shfl_xor(pm1, m, 64));
    pm2 = fmaxf(pm2, __shfl_xor(pm2, m, 64));
    pm3 = fmaxf(pm3, __shfl_xor(pm3, m, 64));
  }
  if ((t & 63) == 0) {
    const int w = t >> 6;
    red[(w << 2) + 0] = pm0;
    red[(w << 2) + 1] = pm1;
    red[(w << 2) + 2] = pm2;
    red[(w << 2) + 3] = pm3;
  }
  __syncthreads();
  const int hd = t >> 6;                // head of this channel
  const float mhead = fmaxf(fmaxf(red[0 + hd], red[4 + hd]),
                            fmaxf(red[8 + hd], red[12 + hd]));
  const float adh = (hd == 0) ? ad4.x : (hd == 1) ? ad4.y : (hd == 2) ? ad4.z : ad4.w;
  // pass2: den and unnormalized aggregate (den identical across wave lanes)
  float den = 0.f, acc = 0.f;
  for (int e = 0; e < deg; ++e) {
    int src = eidx[st + e];                          // uniform
    float av = a_s[((size_t)src << 2) + hd];         // broadcast within wave
    float ez = __expf(lrelu(av + adh) - mhead);
    den += ez;
    acc = fmaf(ez, h[((size_t)src << 8) + t], acc);  // coalesced row read
  }
  float v = acc / den + b1[t];
  float h1 = v > 0.f ? v : (__expf(v) - 1.f);        // elu
  fbf[((size_t)n << 8) + t] = (__bf16)h1;
  hl[t] = h1;
  float s = h1 * h1;
#pragma unroll
  for (int m = 32; m >= 1; m >>= 1) s += __shfl_xor(s, m, 64);
  if ((t & 63) == 0) r2[t >> 6] = s;
  __syncthreads();
  if (t < 16) {
    float a = 0.f;
#pragma unroll 8
    for (int c = 0; c < 256; ++c) a = fmaf(hl[c], W2[(c << 4) + t], a);
    h2g[((size_t)n << 4) + t] = a;
    h2l[t] = a;
  }
  __syncthreads();
  if (t == 0) {
    float sqv = r2[0] + r2[1] + r2[2] + r2[3];
    sq[n] = sqv;
    float ss = 0.f;
#pragma unroll
    for (int o = 0; o < 16; ++o) ss += h2l[o] * as2[o];
    jsg[n] = make_float2((sqv - TH2) * 0.5f, ss);
  } else if (t == 1) {
    float tt = 0.f;
#pragma unroll
    for (int o = 0; o < 16; ++o) tt += h2l[o] * ad2[o];
    t2g[n] = tt;
  }
}

// ---------------- K_conv2: MFMA gram mask + lane-local online softmax + sparse PV ----------
// 256 blocks x 256 threads. Block owns 32 i-rows (fi frags in VGPR, B operand).
// Waves split j: per iter 128 j staged (32/wave), swapped mfma(Fj,Fi) -> lane owns i=lane&31.
// Mask/softmax/o[16] fully lane-local; exp/PV path gated on rare included bits.
__launch_bounds__(256, 1)
__global__ void k_conv2(const __bf16* __restrict__ fbf, const float* __restrict__ sq,
                        const float2* __restrict__ jsg, const float* __restrict__ t2g,
                        const float* __restrict__ h2g, const float* __restrict__ b2,
                        float* __restrict__ out) {
  __shared__ __align__(16) char fjl[2][65536];   // [buf][128 j][512 B] (content XOR-swizzled)
  __shared__ float thrl[2][128];
  __shared__ float s2l[2][128];
  __shared__ float mrg[256][18];                 // per (wave,lane) partial {m,l,o[16]}

  const int t = threadIdx.x;
  const int lane = t & 63;
  const int w = t >> 6;
  const int half = lane >> 5;
  const int rowA = lane & 31;
  const int i0 = blockIdx.x << 5;
  const int jw = w << 5;

  // B-frags: fi row i0+rowA, k = kc*16 + half*8 + e  (one-time, 64 VGPR)
  bf16x8 bfr[16];
  {
    const char* fb = (const char*)fbf + (((size_t)(i0 + rowA)) << 9) + (half << 4);
#pragma unroll
    for (int kc = 0; kc < 16; ++kc) bfr[kc] = *(const bf16x8*)(fb + kc * 32);
  }
  const float sqi = sq[i0 + rowA];
  const float t2i = t2g[i0 + rowA];
  const float gbase = 0.5f * sqi;                // included iff G > gbase + thr_j

  float m = -INFINITY, l = 0.f;
  float o[16];
#pragma unroll
  for (int c = 0; c < 16; ++c) o[c] = 0.f;

#define STAGE(B, JT)                                                                   \
  do {                                                                                 \
    const size_t j0b = ((size_t)(JT)) << 7;                                            \
    _Pragma("unroll") for (int p = 0; p < 16; ++p) {                                   \
      const int r0 = p * 8 + (w << 1);                                                 \
      const int r = r0 + half;                                                         \
      const int cb = (lane & 31) << 4;                                                 \
      const char* src =                                                                \
          (const char*)fbf + ((j0b + r) << 9) + (cb ^ ((r & 31) << 4));                \
      gl_lds16(src, (void*)(fjl[B] + (r0 << 9)));                                      \
    }                                                                                  \
    if (t < 128) {                                                                     \
      float2 v = jsg[j0b + t];                                                         \
      thrl[B][t] = v.x;                                                                \
      s2l[B][t] = v.y;                                                                 \
    }                                                                                  \
  } while (0)

  STAGE(0, 0);
  __syncthreads();
  int cur = 0;

  for (int jt = 0; jt < 64; ++jt) {
    if (jt < 63) STAGE(cur ^ 1, jt + 1);

    // ---- gram: G^T = Fj @ Fi^T via 16 mfma (2 acc chains) ----
    f32x16 acc0, acc1;
#pragma unroll
    for (int r = 0; r < 16; ++r) { acc0[r] = 0.f; acc1[r] = 0.f; }
    const char* fjrow = fjl[cur] + ((size_t)(jw + rowA) << 9);
    const int ksw = half << 4;
    const int rsw = rowA << 4;
#pragma unroll
    for (int kc = 0; kc < 16; kc += 2) {
      bf16x8 a0 = *(const bf16x8*)(fjrow + ((kc * 32 + ksw) ^ rsw));
      bf16x8 a1 = *(const bf16x8*)(fjrow + (((kc + 1) * 32 + ksw) ^ rsw));
      acc0 = __builtin_amdgcn_mfma_f32_32x32x16_bf16(a0, bfr[kc], acc0, 0, 0, 0);
      acc1 = __builtin_amdgcn_mfma_f32_32x32x16_bf16(a1, bfr[kc + 1], acc1, 0, 0, 0);
    }

    // ---- per-lane thr/s2 for the 16 reg-j's: j = jw + (r&3) + 8*(r>>2) + 4*half ----
    const float* tb = thrl[cur] + jw + (half << 2);
    const float* sb = s2l[cur] + jw + (half << 2);
    float4 th0 = *(const float4*)(tb + 0);
    float4 th1 = *(const float4*)(tb + 8);
    float4 th2 = *(const float4*)(tb + 16);
    float4 th3 = *(const float4*)(tb + 24);
    float4 sv0 = *(const float4*)(sb + 0);
    float4 sv1 = *(const float4*)(sb + 8);
    float4 sv2 = *(const float4*)(sb + 16);
    float4 sv3 = *(const float4*)(sb + 24);
    const float thv[16] = {th0.x, th0.y, th0.z, th0.w, th1.x, th1.y, th1.z, th1.w,
                           th2.x, th2.y, th2.z, th2.w, th3.x, th3.y, th3.z, th3.w};
    const float s2v[16] = {sv0.x, sv0.y, sv0.z, sv0.w, sv1.x, sv1.y, sv1.z, sv1.w,
                           sv2.x, sv2.y, sv2.z, sv2.w, sv3.x, sv3.y, sv3.z, sv3.w};

    unsigned msk = 0;
#pragma unroll
    for (int r = 0; r < 16; ++r) {
      float g = acc0[r] + acc1[r];
      if (g > gbase + thv[r]) msk |= (1u << r);
    }

    if (msk) {                                   // rare: lane has included neighbor(s)
      const int j0 = (jt << 7) + jw + (half << 2);
#pragma unroll
      for (int r = 0; r < 16; ++r) {
        if (msk & (1u << r)) {
          float e = lrelu(s2v[r] + t2i);
          if (e > m) {
            float scl = __expf(m - e);
            l *= scl;
#pragma unroll
            for (int c = 0; c < 16; ++c) o[c] *= scl;
            m = e;
          }
          float p = __expf(e - m);
          l += p;
          int j = j0 + (r & 3) + ((r >> 2) << 3);
          const float4* hp = (const float4*)(h2g + ((size_t)j << 4));
          float4 q0 = hp[0], q1 = hp[1], q2 = hp[2], q3 = hp[3];
          o[0] += p * q0.x;  o[1] += p * q0.y;  o[2] += p * q0.z;  o[3] += p * q0.w;
          o[4] += p * q1.x;  o[5] += p * q1.y;  o[6] += p * q1.z;  o[7] += p * q1.w;
          o[8] += p * q2.x;  o[9] += p * q2.y;  o[10] += p * q2.z; o[11] += p * q2.w;
          o[12] += p * q3.x; o[13] += p * q3.y; o[14] += p * q3.z; o[15] += p * q3.w;
        }
      }
    }
    __syncthreads();
    cur ^= 1;
  }

  // ---- merge 8 partials per i (4 waves x 2 halves) ----
  {
    float* mp = mrg[(w << 6) + lane];
    mp[0] = m;
    mp[1] = l;
#pragma unroll
    for (int c = 0; c < 16; ++c) mp[2 + c] = o[c];
  }
  __syncthreads();
  if (t < 32) {
    float M = -INFINITY;
#pragma unroll
    for (int s = 0; s < 8; ++s)
      M = fmaxf(M, mrg[((s >> 1) << 6) + ((s & 1) << 5) + t][0]);
    float L = 0.f, O[16];
#pragma unroll
    for (int c = 0; c < 16; ++c) O[c] = 0.f;
#pragma unroll
    for (int s = 0; s < 8; ++s) {
      const float* mp = mrg[((s >> 1) << 6) + ((s & 1) << 5) + t];
      float wt = __expf(mp[0] - M);              // 0 for empty partials
      L += mp[1] * wt;
#pragma unroll
      for (int c = 0; c < 16; ++c) O[c] += mp[2 + c] * wt;
    }
    // epilogue: normalize, +b2, log_softmax over 16 channels
    float inv = 1.f / L;
    float v[16];
    float mx = -INFINITY;
#pragma unroll
    for (int c = 0; c < 16; ++c) {
      v[c] = O[c] * inv + b2[c];
      mx = fmaxf(mx, v[c]);
    }
    float se = 0.f;
#pragma unroll
    for (int c = 0; c < 16; ++c) se += __expf(v[c] - mx);
    float lse = mx + __logf(se);
    float4* op = (float4*)(out + ((size_t)(i0 + t) << 4));
#pragma unroll
    for (int gq = 0; gq < 4; ++gq)
      op[gq] = make_float4(v[gq * 4 + 0] - lse, v[gq * 4 + 1] - lse,
                           v[gq * 4 + 2] - lse, v[gq * 4 + 3] - lse);
  }
#undef STAGE
}

extern "C" void kernel_launch(void* const* d_in, const int* in_sizes, int n_in,
                              void* d_out, int out_size, void* d_ws, size_t ws_size,
                              hipStream_t stream) {
  const float* x   = (const float*)d_in[0];
  const int*   ei  = (const int*)d_in[1];
  const float* W1  = (const float*)d_in[2];
  const float* as1 = (const float*)d_in[3];
  const float* ad1 = (const float*)d_in[4];
  const float* b1  = (const float*)d_in[5];
  const float* W2  = (const float*)d_in[6];
  const float* as2 = (const float*)d_in[7];
  const float* ad2 = (const float*)d_in[8];
  const float* b2  = (const float*)d_in[9];
  float* out = (float*)d_out;

  float* p = (float*)d_ws;
  float* h    = p; p += (size_t)NN * 256;
  float* a_s  = p; p += (size_t)NN * 4;
  float* a_d  = p; p += (size_t)NN * 4;
  float* sq   = p; p += NN;
  float* t2   = p; p += NN;
  float* h2g  = p; p += (size_t)NN * 16;
  float2* jsg = (float2*)p; p += (size_t)NN * 2;
  __bf16* fbf = (__bf16*)p; p += (size_t)NN * 128;   // NN*256 bf16
  int* cnt    = (int*)p; p += NN;
  int* startp = (int*)p; p += NN;
  int* cursor = (int*)p; p += NN;
  int* eidx   = (int*)p;

  k_init<<<NN / 256, 256, 0, stream>>>(cnt);
  k_hist<<<NE / 256, 256, 0, stream>>>(ei, cnt);
  k_gemm1<<<NN / 4, 256, 0, stream>>>(x, W1, as1, ad1, h, a_s, a_d);
  k_scan<<<1, 1024, 0, stream>>>(cnt, startp, cursor);
  k_scatter<<<(EA + 255) / 256, 256, 0, stream>>>(ei, cursor, eidx);
  k_node<<<NN, 256, 0, stream>>>(startp, cnt, eidx, a_s, a_d, h, b1, W2, as2, ad2,
                                 fbf, sq, jsg, t2, h2g);
  k_conv2<<<NN / 32, 256, 0, stream>>>(fbf, sq, jsg, t2, h2g, b2, out);
}

// Round 6
// 261.351 us; speedup vs baseline: 5.8163x; 1.1915x over previous
//
#include <hip/hip_runtime.h>
#include <hip/hip_bf16.h>
#include <math.h>

#define NN 8192
#define NE 262144
#define EA (NE + NN)          // edges + self loops
#define SLOPE 0.2f
#define TH2 0.25f             // THRESH^2 : dist<0.5  <=>  d2<0.25

typedef __bf16 bf16x8 __attribute__((ext_vector_type(8)));
typedef float f32x16 __attribute__((ext_vector_type(16)));

__device__ __forceinline__ float lrelu(float x) { return x > 0.f ? x : SLOPE * x; }

__device__ __forceinline__ void gl_lds16(const void* g, void* l) {
  __builtin_amdgcn_global_load_lds((const __attribute__((address_space(1))) void*)g,
                                   (__attribute__((address_space(3))) void*)l, 16, 0, 0);
}
__device__ __forceinline__ void gl_lds4(const void* g, void* l) {
  __builtin_amdgcn_global_load_lds((const __attribute__((address_space(1))) void*)g,
                                   (__attribute__((address_space(3))) void*)l, 4, 0, 0);
}

// ---------------- K1: h = x@W1 (4 nodes/block), a_s/a_d head sums ----------------
__global__ void k_gemm1(const float* __restrict__ x, const float* __restrict__ W1,
                        const float* __restrict__ as1, const float* __restrict__ ad1,
                        float* __restrict__ h, float* __restrict__ a_s,
                        float* __restrict__ a_d) {
  const int nb = blockIdx.x << 2;
  const int t = threadIdx.x;
  __shared__ float xs[4][128];
  if (t < 128) ((float4*)xs)[t] = ((const float4*)(x + (size_t)nb * 128))[t];
  __syncthreads();
  float ac[4] = {0.f, 0.f, 0.f, 0.f};
  const float* wp = W1 + t;            // W1 [128][256]
#pragma unroll 4
  for (int k = 0; k < 128; ++k) {
    float wv = wp[(size_t)k << 8];
    ac[0] = fmaf(xs[0][k], wv, ac[0]);
    ac[1] = fmaf(xs[1][k], wv, ac[1]);
    ac[2] = fmaf(xs[2][k], wv, ac[2]);
    ac[3] = fmaf(xs[3][k], wv, ac[3]);
  }
  const float as1t = as1[t], ad1t = ad1[t];
#pragma unroll
  for (int i = 0; i < 4; ++i) {
    h[((size_t)(nb + i) << 8) + t] = ac[i];
    float av = ac[i] * as1t;
    float dv = ac[i] * ad1t;
#pragma unroll
    for (int m = 32; m >= 1; m >>= 1) {
      av += __shfl_xor(av, m, 64);
      dv += __shfl_xor(dv, m, 64);
    }
    if ((t & 63) == 0) {
      a_s[((nb + i) << 2) + (t >> 6)] = av;
      a_d[((nb + i) << 2) + (t >> 6)] = dv;
    }
  }
}

// ---------------- CSR build ----------------
__global__ void k_init(int* __restrict__ cnt) {
  int i = blockIdx.x * 256 + threadIdx.x;
  if (i < NN) cnt[i] = 1;               // self loop pre-counted
}
__global__ void k_hist(const int* __restrict__ ei, int* __restrict__ cnt) {
  int e = blockIdx.x * 256 + threadIdx.x;
  if (e < NE) atomicAdd(&cnt[ei[NE + e]], 1);
}
__global__ void k_scan(const int* __restrict__ cnt, int* __restrict__ start,
                       int* __restrict__ cursor) {
  __shared__ int s[1024];
  const int t = threadIdx.x;
  const int base = t << 3;
  int c[8];
  int run = 0;
#pragma unroll
  for (int i = 0; i < 8; ++i) { c[i] = cnt[base + i]; run += c[i]; }
  s[t] = run;
  __syncthreads();
  const int total = run;
  for (int off = 1; off < 1024; off <<= 1) {
    int v = (t >= off) ? s[t - off] : 0;
    __syncthreads();
    s[t] += v;
    __syncthreads();
  }
  int o = s[t] - total;                 // exclusive prefix
#pragma unroll
  for (int i = 0; i < 8; ++i) {
    start[base + i] = o;
    cursor[base + i] = o;
    o += c[i];
  }
}
__global__ void k_scatter(const int* __restrict__ ei, int* __restrict__ cursor,
                          int* __restrict__ eidx) {
  int e = blockIdx.x * 256 + threadIdx.x;
  if (e >= EA) return;
  int src, dst;
  if (e < NE) { src = ei[e]; dst = ei[NE + e]; } else { src = dst = e - NE; }
  int slot = atomicAdd(&cursor[dst], 1);
  eidx[slot] = src;
}

// ---------------- K_node: fused segment max + softmax + aggregate + post ----------------
// one block (256 threads) per dst node; thread t owns channel t; no f32 atomics.
__global__ void k_node(const int* __restrict__ start, const int* __restrict__ cnt,
                       const int* __restrict__ eidx, const float* __restrict__ a_s,
                       const float* __restrict__ a_d, const float* __restrict__ h,
                       const float* __restrict__ b1, const float* __restrict__ W2,
                       const float* __restrict__ as2, const float* __restrict__ ad2,
                       __bf16* __restrict__ fbf, float* __restrict__ sq,
                       float* __restrict__ thr_g, float* __restrict__ s2_g,
                       float* __restrict__ t2g, float* __restrict__ h2g) {
  const int n = blockIdx.x, t = threadIdx.x;
  __shared__ float red[16];             // [wave][head]
  __shared__ float hl[256];
  __shared__ float r2[4];
  __shared__ float h2l[16];
  const int st = start[n];
  const int deg = cnt[n];
  const float4 ad4 = *(const float4*)(a_d + ((size_t)n << 2));
  // pass1: per-head max over incoming edges
  float pm0 = -INFINITY, pm1 = -INFINITY, pm2 = -INFINITY, pm3 = -INFINITY;
  for (int e = t; e < deg; e += 256) {
    int src = eidx[st + e];
    float4 s4 = *(const float4*)(a_s + ((size_t)src << 2));
    pm0 = fmaxf(pm0, lrelu(s4.x + ad4.x));
    pm1 = fmaxf(pm1, lrelu(s4.y + ad4.y));
    pm2 = fmaxf(pm2, lrelu(s4.z + ad4.z));
    pm3 = fmaxf(pm3, lrelu(s4.w + ad4.w));
  }
#pragma unroll
  for (int m = 32; m >= 1; m >>= 1) {
    pm0 = fmaxf(pm0, __shfl_xor(pm0, m, 64));
    pm1 = fmaxf(pm1, __shfl_xor(pm1, m, 64));
    pm2 = fmaxf(pm2, __shfl_xor(pm2, m, 64));
    pm3 = fmaxf(pm3, __shfl_xor(pm3, m, 64));
  }
  if ((t & 63) == 0) {
    const int w = t >> 6;
    red[(w << 2) + 0] = pm0;
    red[(w << 2) + 1] = pm1;
    red[(w << 2) + 2] = pm2;
    red[(w << 2) + 3] = pm3;
  }
  __syncthreads();
  const int hd = t >> 6;                // head of this channel
  const float mhead = fmaxf(fmaxf(red[0 + hd], red[4 + hd]),
                            fmaxf(red[8 + hd], red[12 + hd]));
  const float adh = (hd == 0) ? ad4.x : (hd == 1) ? ad4.y : (hd == 2) ? ad4.z : ad4.w;
  // pass2: den and unnormalized aggregate, 4-way unrolled (independent chains)
  float dn0 = 0.f, dn1 = 0.f, dn2 = 0.f, dn3 = 0.f;
  float ac0 = 0.f, ac1 = 0.f, ac2 = 0.f, ac3 = 0.f;
  int e = 0;
  for (; e + 3 < deg; e += 4) {
    int s0 = eidx[st + e + 0], s1 = eidx[st + e + 1];
    int s2i = eidx[st + e + 2], s3 = eidx[st + e + 3];
    float z0 = __expf(lrelu(a_s[((size_t)s0 << 2) + hd] + adh) - mhead);
    float z1 = __expf(lrelu(a_s[((size_t)s1 << 2) + hd] + adh) - mhead);
    float z2 = __expf(lrelu(a_s[((size_t)s2i << 2) + hd] + adh) - mhead);
    float z3 = __expf(lrelu(a_s[((size_t)s3 << 2) + hd] + adh) - mhead);
    dn0 += z0; dn1 += z1; dn2 += z2; dn3 += z3;
    ac0 = fmaf(z0, h[((size_t)s0 << 8) + t], ac0);
    ac1 = fmaf(z1, h[((size_t)s1 << 8) + t], ac1);
    ac2 = fmaf(z2, h[((size_t)s2i << 8) + t], ac2);
    ac3 = fmaf(z3, h[((size_t)s3 << 8) + t], ac3);
  }
  for (; e < deg; ++e) {
    int s0 = eidx[st + e];
    float z0 = __expf(lrelu(a_s[((size_t)s0 << 2) + hd] + adh) - mhead);
    dn0 += z0;
    ac0 = fmaf(z0, h[((size_t)s0 << 8) + t], ac0);
  }
  float den = (dn0 + dn1) + (dn2 + dn3);
  float acc = (ac0 + ac1) + (ac2 + ac3);
  float v = acc / den + b1[t];
  float h1 = v > 0.f ? v : (__expf(v) - 1.f);        // elu
  fbf[((size_t)n << 8) + t] = (__bf16)h1;
  hl[t] = h1;
  float s = h1 * h1;
#pragma unroll
  for (int m = 32; m >= 1; m >>= 1) s += __shfl_xor(s, m, 64);
  if ((t & 63) == 0) r2[t >> 6] = s;
  __syncthreads();
  if (t < 16) {
    float a = 0.f;
#pragma unroll 8
    for (int c = 0; c < 256; ++c) a = fmaf(hl[c], W2[(c << 4) + t], a);
    h2g[((size_t)n << 4) + t] = a;
    h2l[t] = a;
  }
  __syncthreads();
  if (t == 0) {
    float sqv = r2[0] + r2[1] + r2[2] + r2[3];
    sq[n] = sqv;
    float ss = 0.f;
#pragma unroll
    for (int o = 0; o < 16; ++o) ss += h2l[o] * as2[o];
    thr_g[n] = (sqv - TH2) * 0.5f;
    s2_g[n] = ss;
  } else if (t == 1) {
    float tt = 0.f;
#pragma unroll
    for (int o = 0; o < 16; ++o) tt += h2l[o] * ad2[o];
    t2g[n] = tt;
  }
}

// ---------------- K_conv2: barrier-free counted-vmcnt pipeline ----------------
// 256 blocks x 256 threads. Block owns 32 i (B-frags in VGPR). Each wave owns its
// own 32-j window per tile, staged into per-wave LDS (no cross-wave sharing ->
// NO __syncthreads in the main loop; s_waitcnt vmcnt(20) gates buffer reuse).
__launch_bounds__(256, 1)
__global__ void k_conv2(const __bf16* __restrict__ fbf, const float* __restrict__ sq,
                        const float* __restrict__ thr_g, const float* __restrict__ s2_g,
                        const float* __restrict__ t2g, const float* __restrict__ h2g,
                        const float* __restrict__ b2, float* __restrict__ out) {
  // per wave: 2 bufs x (16KB fj + 512B thr + 512B s2) = 34816B; 4 waves = 136KB
  __shared__ __align__(16) char pool[139264];

  const int t = threadIdx.x;
  const int lane = t & 63;
  const int w = t >> 6;
  const int half = lane >> 5;
  const int lo = lane & 31;
  const int rowA = lo;
  const int i0 = blockIdx.x << 5;
  const int jw = w << 5;
  char* wbase = pool + w * 34816;

  // per-lane stage source offsets (XOR-pre-swizzled global, m173 pattern)
  int stoff[16];
#pragma unroll
  for (int p = 0; p < 16; ++p) {
    int rw = (p << 1) + half;
    stoff[p] = ((jw + rw) << 9) + (((lo ^ rw) & 31) << 4);
  }
  // per-lane swizzled read offsets within own row
  int colkey[16];
#pragma unroll
  for (int kc = 0; kc < 16; ++kc)
    colkey[kc] = ((((kc << 1) + half) ^ rowA) & 31) << 4;

  // B-frags: fi row i0+rowA (64 VGPR, one-time)
  bf16x8 bfr[16];
  {
    const char* fb = (const char*)fbf + (((size_t)(i0 + rowA)) << 9) + (half << 4);
#pragma unroll
    for (int kc = 0; kc < 16; ++kc) bfr[kc] = *(const bf16x8*)(fb + kc * 32);
  }
  const float sqi = sq[i0 + rowA];
  const float t2i = t2g[i0 + rowA];
  const float gb_i = 0.5f * sqi;                 // included iff G > gb_i + thr_j

  float m = -INFINITY, l = 0.f;
  float o[16];
#pragma unroll
  for (int c = 0; c < 16; ++c) o[c] = 0.f;

#define STAGE(B, JT)                                                        \
  do {                                                                      \
    const char* gsrc = (const char*)fbf + ((size_t)(JT) << 16);             \
    char* lb_ = wbase + (B)*17408;                                          \
    _Pragma("unroll") for (int p = 0; p < 16; ++p)                          \
        gl_lds16(gsrc + stoff[p], lb_ + (p << 10));                         \
    gl_lds4(thr_g + ((JT) << 7) + lane, lb_ + 16384);                       \
    gl_lds4(thr_g + ((JT) << 7) + 64 + lane, lb_ + 16384 + 256);            \
    gl_lds4(s2_g + ((JT) << 7) + lane, lb_ + 16896);                        \
    gl_lds4(s2_g + ((JT) << 7) + 64 + lane, lb_ + 16896 + 256);             \
  } while (0)

  STAGE(0, 0);

  for (int jt = 0; jt < 64; ++jt) {
    const int cur = jt & 1;
    if (jt < 63) {
      STAGE(cur ^ 1, jt + 1);
      asm volatile("s_waitcnt vmcnt(20)" ::: "memory");   // buf cur ready; next stays in flight
    } else {
      asm volatile("s_waitcnt vmcnt(0)" ::: "memory");
    }
    char* lb = wbase + cur * 17408;
    const char* rb = lb + (rowA << 9);

    // ---- gram: G^T = Fj @ Fi^T, 16 mfma (2 chains) ----
    f32x16 acc0, acc1;
#pragma unroll
    for (int r = 0; r < 16; ++r) { acc0[r] = 0.f; acc1[r] = 0.f; }
#pragma unroll
    for (int kc = 0; kc < 16; kc += 2) {
      bf16x8 a0 = *(const bf16x8*)(rb + colkey[kc]);
      bf16x8 a1 = *(const bf16x8*)(rb + colkey[kc + 1]);
      acc0 = __builtin_amdgcn_mfma_f32_32x32x16_bf16(a0, bfr[kc], acc0, 0, 0, 0);
      acc1 = __builtin_amdgcn_mfma_f32_32x32x16_bf16(a1, bfr[kc + 1], acc1, 0, 0, 0);
    }

    // ---- per-lane thr/s2 for the 16 reg-j's (broadcast LDS reads) ----
    const float* thp = (const float*)(lb + 16384);
    const float* s2p = (const float*)(lb + 16896);
    float4 thq[4], s2q[4];
#pragma unroll
    for (int q = 0; q < 4; ++q) {
      thq[q] = *(const float4*)(thp + jw + (half << 2) + (q << 3));
      s2q[q] = *(const float4*)(s2p + jw + (half << 2) + (q << 3));
    }
    const float thv[16] = {thq[0].x, thq[0].y, thq[0].z, thq[0].w,
                           thq[1].x, thq[1].y, thq[1].z, thq[1].w,
                           thq[2].x, thq[2].y, thq[2].z, thq[2].w,
                           thq[3].x, thq[3].y, thq[3].z, thq[3].w};
    const float s2v[16] = {s2q[0].x, s2q[0].y, s2q[0].z, s2q[0].w,
                           s2q[1].x, s2q[1].y, s2q[1].z, s2q[1].w,
                           s2q[2].x, s2q[2].y, s2q[2].z, s2q[2].w,
                           s2q[3].x, s2q[3].y, s2q[3].z, s2q[3].w};

    unsigned msk = 0;
#pragma unroll
    for (int r = 0; r < 16; ++r) {
      float g = acc0[r] + acc1[r];
      if (g > gb_i + thv[r]) msk |= (1u << r);
    }

    if (msk) {                                   // rare: included neighbor(s)
      const int j0 = (jt << 7) + jw + (half << 2);
#pragma unroll
      for (int r = 0; r < 16; ++r) {
        if (msk & (1u << r)) {
          float e = lrelu(s2v[r] + t2i);
          if (e > m) {
            float scl = __expf(m - e);
            l *= scl;
#pragma unroll
            for (int c = 0; c < 16; ++c) o[c] *= scl;
            m = e;
          }
          float p = __expf(e - m);
          l += p;
          int j = j0 + (r & 3) + ((r >> 2) << 3);
          const float4* hp = (const float4*)(h2g + ((size_t)j << 4));
          float4 q0 = hp[0], q1 = hp[1], q2 = hp[2], q3 = hp[3];
          o[0] += p * q0.x;  o[1] += p * q0.y;  o[2] += p * q0.z;  o[3] += p * q0.w;
          o[4] += p * q1.x;  o[5] += p * q1.y;  o[6] += p * q1.z;  o[7] += p * q1.w;
          o[8] += p * q2.x;  o[9] += p * q2.y;  o[10] += p * q2.z; o[11] += p * q2.w;
          o[12] += p * q3.x; o[13] += p * q3.y; o[14] += p * q3.z; o[15] += p * q3.w;
        }
      }
    }
  }

  // ---- merge 8 partials per i (4 waves x 2 halves); reuse pool ----
  __syncthreads();
  float (*mrg)[18] = (float(*)[18])pool;
  {
    float* mp = mrg[t];
    mp[0] = m;
    mp[1] = l;
#pragma unroll
    for (int c = 0; c < 16; ++c) mp[2 + c] = o[c];
  }
  __syncthreads();
  if (t < 32) {
    float M = -INFINITY;
#pragma unroll
    for (int s = 0; s < 8; ++s)
      M = fmaxf(M, mrg[((s >> 1) << 6) + ((s & 1) << 5) + t][0]);
    float L = 0.f, O[16];
#pragma unroll
    for (int c = 0; c < 16; ++c) O[c] = 0.f;
#pragma unroll
    for (int s = 0; s < 8; ++s) {
      const float* mp = mrg[((s >> 1) << 6) + ((s & 1) << 5) + t];
      float wt = __expf(mp[0] - M);              // 0 for empty partials
      L += mp[1] * wt;
#pragma unroll
      for (int c = 0; c < 16; ++c) O[c] += mp[2 + c] * wt;
    }
    float inv = 1.f / L;
    float v[16];
    float mx = -INFINITY;
#pragma unroll
    for (int c = 0; c < 16; ++c) {
      v[c] = O[c] * inv + b2[c];
      mx = fmaxf(mx, v[c]);
    }
    float se = 0.f;
#pragma unroll
    for (int c = 0; c < 16; ++c) se += __expf(v[c] - mx);
    float lse = mx + __logf(se);
    float4* op = (float4*)(out + ((size_t)(i0 + t) << 4));
#pragma unroll
    for (int gq = 0; gq < 4; ++gq)
      op[gq] = make_float4(v[gq * 4 + 0] - lse, v[gq * 4 + 1] - lse,
                           v[gq * 4 + 2] - lse, v[gq * 4 + 3] - lse);
  }
#undef STAGE
}

extern "C" void kernel_launch(void* const* d_in, const int* in_sizes, int n_in,
                              void* d_out, int out_size, void* d_ws, size_t ws_size,
                              hipStream_t stream) {
  const float* x   = (const float*)d_in[0];
  const int*   ei  = (const int*)d_in[1];
  const float* W1  = (const float*)d_in[2];
  const float* as1 = (const float*)d_in[3];
  const float* ad1 = (const float*)d_in[4];
  const float* b1  = (const float*)d_in[5];
  const float* W2  = (const float*)d_in[6];
  const float* as2 = (const float*)d_in[7];
  const float* ad2 = (const float*)d_in[8];
  const float* b2  = (const float*)d_in[9];
  float* out = (float*)d_out;

  float* p = (float*)d_ws;
  float* h     = p; p += (size_t)NN * 256;
  float* a_s   = p; p += (size_t)NN * 4;
  float* a_d   = p; p += (size_t)NN * 4;
  float* sq    = p; p += NN;
  float* t2    = p; p += NN;
  float* h2g   = p; p += (size_t)NN * 16;
  float* thr_g = p; p += NN;
  float* s2_g  = p; p += NN;
  __bf16* fbf  = (__bf16*)p; p += (size_t)NN * 128;   // NN*256 bf16
  int* cnt     = (int*)p; p += NN;
  int* startp  = (int*)p; p += NN;
  int* cursor  = (int*)p; p += NN;
  int* eidx    = (int*)p;

  k_init<<<NN / 256, 256, 0, stream>>>(cnt);
  k_hist<<<NE / 256, 256, 0, stream>>>(ei, cnt);
  k_gemm1<<<NN / 4, 256, 0, stream>>>(x, W1, as1, ad1, h, a_s, a_d);
  k_scan<<<1, 1024, 0, stream>>>(cnt, startp, cursor);
  k_scatter<<<(EA + 255) / 256, 256, 0, stream>>>(ei, cursor, eidx);
  k_node<<<NN, 256, 0, stream>>>(startp, cnt, eidx, a_s, a_d, h, b1, W2, as2, ad2,
                                 fbf, sq, thr_g, s2_g, t2, h2g);
  k_conv2<<<NN / 32, 256, 0, stream>>>(fbf, sq, thr_g, s2_g, t2, h2g, b2, out);
}